// Round 8
// baseline (193.758 us; speedup 1.0000x reference)
//
#include <hip/hip_runtime.h>
#include <hip/hip_bf16.h>

using bf16 = __hip_bfloat16;
typedef short short8  __attribute__((ext_vector_type(8)));
typedef short short4v __attribute__((ext_vector_type(4)));
typedef float float4v __attribute__((ext_vector_type(4)));
typedef float f32x16  __attribute__((ext_vector_type(16)));
typedef unsigned int uint4v __attribute__((ext_vector_type(4)));

#define MFMA_BF16   __builtin_amdgcn_mfma_f32_16x16x32_bf16
#define MFMA32_BF16 __builtin_amdgcn_mfma_f32_32x32x16_bf16

// Problem constants
#define B_  4
#define S_  2048
#define D_  512
#define H_  8
#define DK_ 64

__device__ __forceinline__ short f2bf(float f) {
  bf16 h = __float2bfloat16(f);
  return *reinterpret_cast<short*>(&h);
}

__device__ __forceinline__ unsigned cvtpk(float lo, float hi) {
  unsigned r;
  asm("v_cvt_pk_bf16_f32 %0, %1, %2" : "=v"(r) : "v"(lo), "v"(hi));
  return r;
}

__device__ __forceinline__ void plswap(unsigned& a, unsigned& b) {
  asm("v_permlane32_swap_b32 %0, %1" : "+v"(a), "+v"(b));
}

__device__ __forceinline__ short8 mk8(unsigned v0, unsigned v1, unsigned v2,
                                      unsigned v3) {
  uint4v u;
  u[0] = v0; u[1] = v1; u[2] = v2; u[3] = v3;
  return __builtin_bit_cast(short8, u);
}

#define GLL(g, l) __builtin_amdgcn_global_load_lds(                        \
      (const __attribute__((address_space(1))) void*)(g),                  \
      (__attribute__((address_space(3))) void*)(l), 16, 0, 0)

// ---------------------------------------------------------------------------
// prep: (blocks 0..6143) fp32->bf16 conversion of q/k/v inputs -> Xb,
//       (blocks 6144..6399) weight transpose -> canonical bf16 B^T layout.
// ---------------------------------------------------------------------------
__global__ __launch_bounds__(256)
void prep(const float* __restrict__ qin, const float* __restrict__ kin,
          const float* __restrict__ vin, short* __restrict__ Xb,
          const float* __restrict__ Wq, const float* __restrict__ Wk,
          const float* __restrict__ Wv, const float* __restrict__ Wo,
          short* __restrict__ WqT, short* __restrict__ WkT,
          short* __restrict__ WvT, short* __restrict__ WoT) {
  __shared__ float tile[64 * 65];
  const int bid = blockIdx.x, tid = threadIdx.x;
  const size_t NTOK = (size_t)B_ * S_ * D_;

  if (bid < 6144) {
    const int z = bid >> 11, blk = bid & 2047;
    const float* src = (z == 0) ? qin : (z == 1) ? kin : vin;
    short* dst = Xb + (size_t)z * NTOK;
    const size_t base = ((size_t)blk * 256 + tid) * 8;
    float4v f0 = *(const float4v*)&src[base];
    float4v f1 = *(const float4v*)&src[base + 4];
    short8 s;
#pragma unroll
    for (int j = 0; j < 4; j++) { s[j] = f2bf(f0[j]); s[j + 4] = f2bf(f1[j]); }
    *(short8*)&dst[base] = s;
    return;
  }

  const int tw = bid - 6144;
  const int mat = tw >> 6, t = tw & 63;
  const float* W = (mat == 0) ? Wq : (mat == 1) ? Wk : (mat == 2) ? Wv : Wo;
  short* T       = (mat == 0) ? WqT : (mat == 1) ? WkT : (mat == 2) ? WvT : WoT;

  size_t sbase, ss, dbase;
  if (mat < 3) {
    int hh = t >> 3, d0 = (t & 7) * 64;
    sbase = (size_t)hh * 32768 + (size_t)d0 * 64;
    ss = 64;
    dbase = (size_t)hh * 64 * 512 + d0;
  } else {
    int n0 = (t >> 3) * 64, k0 = (t & 7) * 64;
    sbase = (size_t)k0 * 512 + n0;
    ss = 512;
    dbase = (size_t)n0 * 512 + k0;
  }

  {
    int r = tid >> 2, c0 = (tid & 3) * 16;
#pragma unroll
    for (int j = 0; j < 4; j++)
      *(float4v*)&tile[r * 65 + c0 + j * 4] =
          *(const float4v*)&W[sbase + (size_t)r * ss + c0 + j * 4];
  }
  __syncthreads();
  {
    int c = tid >> 2, r0 = (tid & 3) * 16;
#pragma unroll
    for (int j = 0; j < 2; j++) {
      short8 s;
#pragma unroll
      for (int u = 0; u < 8; u++) s[u] = f2bf(tile[(r0 + j * 8 + u) * 65 + c]);
      *(short8*)&T[dbase + (size_t)c * 512 + r0 + j * 8] = s;
    }
  }
}

// ---------------------------------------------------------------------------
// GEMM core v3 (round-7, passing): BK=32, double-buffered, interleaved A|B
// LDS tile with involution p = c ^ (row&7) applied on the per-lane GLOBAL
// source (LDS dest linear -- rule #21). 16 K-steps, 1 barrier/step.
// LDS 32 KiB -> 4 blocks/CU.
// ---------------------------------------------------------------------------
__device__ __forceinline__ void gemm_core3(const short* __restrict__ A,
                                           const short* __restrict__ Bt,
                                           int m0, int n0,
                                           short* ABs,
                                           float4v acc[4][4]) {
  const int tid  = threadIdx.x;
  const int lane = tid & 63, wave = tid >> 6;
  const int quad = lane >> 4, l16 = lane & 15;
  const int wm = (wave >> 1) * 64, wn = (wave & 1) * 64;

  auto stage = [&](int buf, int k0) {
#pragma unroll
    for (int i = 0; i < 4; i++) {
      int q = (wave * 4 + i) * 64 + lane;      // chunk id 0..1023
      int row = q >> 3, p = q & 7;
      int c = p ^ (row & 7);                    // logical chunk at this slot
      const short* src = (c < 4)
          ? &A [(size_t)(m0 + row) * 512 + k0 + c * 8]
          : &Bt[(size_t)(n0 + row) * 512 + k0 + (c - 4) * 8];
      GLL(src, &ABs[buf * 8192 + (wave * 4 + i) * 512]);
    }
  };
  auto comp = [&](int buf) {
    short8 af[4], bfr[4];
#pragma unroll
    for (int mi = 0; mi < 4; mi++) {
      int row = wm + mi * 16 + l16;
      af[mi] = *(short8*)&ABs[buf * 8192 + row * 64 + ((quad ^ (row & 7)) << 3)];
    }
#pragma unroll
    for (int ni = 0; ni < 4; ni++) {
      int row = wn + ni * 16 + l16;
      bfr[ni] = *(short8*)&ABs[buf * 8192 + row * 64 +
                               (((4 + quad) ^ (row & 7)) << 3)];
    }
#pragma unroll
    for (int mi = 0; mi < 4; mi++)
#pragma unroll
      for (int ni = 0; ni < 4; ni++)
        acc[mi][ni] = MFMA_BF16(af[mi], bfr[ni], acc[mi][ni], 0, 0, 0);
  };

  stage(0, 0);
  __syncthreads();
#pragma unroll
  for (int k = 0; k < 512; k += 64) {
    stage(1, k + 32);            // prefetch odd tile
    comp(0);                     // compute even tile
    __syncthreads();
    if (k + 64 < 512) stage(0, k + 64);   // prefetch next even tile
    comp(1);                     // compute odd tile
    __syncthreads();
  }
}

// ---------------------------------------------------------------------------
// QKV projection from pre-converted bf16 Xb.
// z=0: Q -> [B,H,S,64] scaled log2e/8; z=1: K -> [B,H,S,64].
// z=2: V with SWAPPED operand roles: C[hv][s] = WvT[hv] . Xv[s] so the
//      Vt[B,H,64,S] store is contiguous in s (32B segments, no 4KB scatter).
//      blockIdx roles swap for z=2: x=s-tiles(64), y=hv-tiles(4).
// ---------------------------------------------------------------------------
__global__ __launch_bounds__(256, 4)
void qkv_gemm(const short* __restrict__ Xb,
              const short* __restrict__ WqT, const short* __restrict__ WkT,
              const short* __restrict__ WvT,
              const float* __restrict__ bq, const float* __restrict__ bk,
              const float* __restrict__ bv,
              short* __restrict__ Qp, short* __restrict__ Kp,
              short* __restrict__ Vt) {
  __shared__ __align__(16) short ABs[2 * 8192];   // 32 KiB
  const int z = blockIdx.z;
  const int m0 = (z == 2) ? blockIdx.y * 128 : blockIdx.x * 128;
  const int n0 = (z == 2) ? blockIdx.x * 128 : blockIdx.y * 128;
  const size_t NTOK = (size_t)B_ * S_ * D_;
  const short* A    = (z == 2) ? WvT : Xb + (size_t)z * NTOK;
  const short* Bt   = (z == 0) ? WqT : (z == 1) ? WkT : Xb + 2 * NTOK;
  const float* bias = (z == 0) ? bq  : (z == 1) ? bk  : bv;
  const float scale = (z == 0) ? 0.125f * 1.44269504088896f : 1.0f;

  float4v acc[4][4];
#pragma unroll
  for (int mi = 0; mi < 4; mi++)
#pragma unroll
    for (int ni = 0; ni < 4; ni++) acc[mi][ni] = (float4v){0.f, 0.f, 0.f, 0.f};

  gemm_core3(A, Bt, m0, n0, ABs, acc);

  const int lane = threadIdx.x & 63, wave = threadIdx.x >> 6;
  const int quad = lane >> 4, l16 = lane & 15;
  const int wm = (wave >> 1) * 64, wn = (wave & 1) * 64;

  if (z < 2) {
    short* out = (z == 0) ? Qp : Kp;
#pragma unroll
    for (int mi = 0; mi < 4; mi++) {
      int m = m0 + wm + mi * 16 + quad * 4;
      int b = m >> 11, s = m & 2047;
#pragma unroll
      for (int ni = 0; ni < 4; ni++) {
        int n = n0 + wn + ni * 16 + l16;
        int h = n >> 6, dk = n & 63;
        float bb = bias[n];
        size_t base = (((size_t)b * H_ + h) * S_ + s) * 64 + dk;
#pragma unroll
        for (int r = 0; r < 4; r++)
          out[base + (size_t)r * 64] = f2bf((acc[mi][ni][r] + bb) * scale);
      }
    }
  } else {
    // rows m = hv (h*64+v), cols n = global s. Store contiguous in s.
#pragma unroll
    for (int mi = 0; mi < 4; mi++) {
      int m = m0 + wm + mi * 16 + quad * 4;
#pragma unroll
      for (int r = 0; r < 4; r++) {
        int hv = m + r;
        int h = hv >> 6, v = hv & 63;
        float bb = bias[hv];
#pragma unroll
        for (int ni = 0; ni < 4; ni++) {
          int n = n0 + wn + ni * 16 + l16;
          int b = n >> 11, sl = n & 2047;
          Vt[(((size_t)b * H_ + h) * 64 + v) * S_ + sl] =
              f2bf(acc[mi][ni][r] + bb);
        }
      }
    }
  }
}

// ---------------------------------------------------------------------------
// Flash attention v5: 512 thr = 8 waves; waves 0-3 KV [0,1024), waves 4-7
// KV [1024,2048) for the same 128 Q rows (wg=wave&3 owns 32 rows).
// Swapped-operand 32x32x16 MFMA, in-register softmax (cvt_pk+permlane32).
// Row-sum l computed ON THE MFMA PIPE via ones-vector: acc_l = mfma(pa, 1)
// -> lands in C-layout rows, so epilogue needs no shuffles.
// No-rescale softmax; halves combined through LDS at the end.
// LDS 64 KiB: K[half][buf][4096] | V[half][buf][4096].
// ---------------------------------------------------------------------------
__global__ __launch_bounds__(512, 4)
void attn_kernel(const short* __restrict__ Qp, const short* __restrict__ Kp,
                 const short* __restrict__ Vt, short* __restrict__ Ao) {
  __shared__ __align__(16) short sh[32768];   // 64 KiB

  const int orig = blockIdx.y * gridDim.x + blockIdx.x;
  const int lb = (orig & 7) * 64 + (orig >> 3);   // bijective XCD swizzle
  const int qt = lb & 15, bh = lb >> 4;
  const int b = bh >> 3, h = bh & 7;

  const int tid = threadIdx.x;
  const int lane = tid & 63, wave = tid >> 6;
  const int wg = wave & 3, half = wave >> 2;
  const int l31 = lane & 31, hi = lane >> 5, s7 = l31 & 7;

  const short* Qb = Qp + (size_t)bh * S_ * 64;
  const short* Kb = Kp + (size_t)bh * S_ * 64 + (size_t)half * 1024 * 64;
  const short* Vb = Vt + (size_t)bh * 64 * S_;

  short8 qf[4];
  {
    const short* qrow = Qb + (size_t)(qt * 128 + wg * 32 + l31) * 64;
#pragma unroll
    for (int w = 0; w < 4; w++)
      qf[w] = *(const short8*)&qrow[w * 16 + hi * 8];
  }

  short8 ones8;
#pragma unroll
  for (int j = 0; j < 8; j++) ones8[j] = (short)0x3F80;   // bf16 1.0

  const int slot0 = wg * 128 + lane;
  const int kr0 = slot0 >> 3, kc0 = slot0 & 7;
  const int kr1 = kr0 + 8;
  const short* kg0 = Kb + (size_t)kr0 * 64 + ((kc0 ^ (kr0 & 7)) << 3);
  const short* kg1 = Kb + (size_t)kr1 * 64 + ((kc0 ^ (kr1 & 7)) << 3);
  const short* vg0 = Vb + (size_t)kr0 * S_ + half * 1024 + ((kc0 ^ (kr0 & 7)) << 3);
  const short* vg1 = Vb + (size_t)kr1 * S_ + half * 1024 + ((kc0 ^ (kr1 & 7)) << 3);

  short* Kbase = sh;            // [half*2+buf][4096]
  short* Vbase = sh + 16384;

  f32x16 acc0, acc1, accl;
#pragma unroll
  for (int r = 0; r < 16; r++) { acc0[r] = 0.f; acc1[r] = 0.f; accl[r] = 0.f; }

  {
    short* kd = Kbase + (half * 2) * 4096 + wg * 1024;
    short* vd = Vbase + (half * 2) * 4096 + wg * 1024;
    GLL(kg0, kd); GLL(kg1, kd + 512);
    GLL(vg0, vd); GLL(vg1, vd + 512);
  }
  __syncthreads();

  for (int t = 0; t < 16; t++) {
    const int cur = t & 1;
    if (t < 15) {
      short* kd = Kbase + (half * 2 + (cur ^ 1)) * 4096 + wg * 1024;
      short* vd = Vbase + (half * 2 + (cur ^ 1)) * 4096 + wg * 1024;
      GLL(kg0 + (size_t)(t + 1) * 4096, kd);
      GLL(kg1 + (size_t)(t + 1) * 4096, kd + 512);
      GLL(vg0 + (size_t)(t + 1) * 64, vd);
      GLL(vg1 + (size_t)(t + 1) * 64, vd + 512);
    }
    const short* kb = Kbase + (half * 2 + cur) * 4096;
    const short* vs = Vbase + (half * 2 + cur) * 4096;

#pragma unroll
    for (int kt = 0; kt < 2; kt++) {
      f32x16 sa;
#pragma unroll
      for (int r = 0; r < 16; r++) sa[r] = 0.f;
      __builtin_amdgcn_s_setprio(1);
#pragma unroll
      for (int w = 0; w < 4; w++) {
        short8 kf = *(const short8*)&kb[(kt * 32 + l31) * 64 +
                                        (((2 * w + hi) ^ s7) << 3)];
        sa = MFMA32_BF16(kf, qf[w], sa, 0, 0, 0);
      }
      __builtin_amdgcn_s_setprio(0);

      float pv[16];
#pragma unroll
      for (int r = 0; r < 16; r++) pv[r] = exp2f(sa[r]);

      unsigned a0 = cvtpk(pv[0], pv[1]),  b0 = cvtpk(pv[4], pv[5]);
      plswap(a0, b0);
      unsigned c0 = cvtpk(pv[2], pv[3]),  d0 = cvtpk(pv[6], pv[7]);
      plswap(c0, d0);
      short8 pa0 = mk8(a0, c0, b0, d0);
      unsigned a1 = cvtpk(pv[8], pv[9]),  b1 = cvtpk(pv[12], pv[13]);
      plswap(a1, b1);
      unsigned c1 = cvtpk(pv[10], pv[11]), d1 = cvtpk(pv[14], pv[15]);
      plswap(c1, d1);
      short8 pa1 = mk8(a1, c1, b1, d1);

      __builtin_amdgcn_s_setprio(1);
      // row-sum on MFMA pipe: accl[r] = l for q-row crow(r,hi)
      accl = MFMA32_BF16(pa0, ones8, accl, 0, 0, 0);
      accl = MFMA32_BF16(pa1, ones8, accl, 0, 0, 0);
      {
        const int kw0 = kt * 2, kw1 = kt * 2 + 1;
        short8 v00 = *(const short8*)&vs[l31 * 64 + (((2 * kw0 + hi) ^ s7) << 3)];
        short8 v10 = *(const short8*)&vs[(32 + l31) * 64 + (((2 * kw0 + hi) ^ s7) << 3)];
        acc0 = MFMA32_BF16(pa0, v00, acc0, 0, 0, 0);
        acc1 = MFMA32_BF16(pa0, v10, acc1, 0, 0, 0);
        short8 v01 = *(const short8*)&vs[l31 * 64 + (((2 * kw1 + hi) ^ s7) << 3)];
        short8 v11 = *(const short8*)&vs[(32 + l31) * 64 + (((2 * kw1 + hi) ^ s7) << 3)];
        acc0 = MFMA32_BF16(pa1, v01, acc0, 0, 0, 0);
        acc1 = MFMA32_BF16(pa1, v11, acc1, 0, 0, 0);
      }
      __builtin_amdgcn_s_setprio(0);
    }
    __syncthreads();
  }

  // combine halves through LDS (acc0/acc1 per-lane blocks; accl per-row)
  float* fsh = (float*)sh;
  if (half == 1) {
    const int base = wg * 2304 + lane * 36;
#pragma unroll
    for (int r = 0; r < 16; r += 4) {
      *(float4v*)&fsh[base + r] =
          (float4v){acc0[r], acc0[r + 1], acc0[r + 2], acc0[r + 3]};
      *(float4v*)&fsh[base + 16 + r] =
          (float4v){acc1[r], acc1[r + 1], acc1[r + 2], acc1[r + 3]};
    }
    if (l31 == 0) {       // lanes 0 and 32 cover all 32 rows
#pragma unroll
      for (int r = 0; r < 16; r++)
        fsh[9216 + wg * 32 + (r & 3) + 8 * (r >> 2) + 4 * hi] = accl[r];
    }
  }
  __syncthreads();
  if (half == 1) return;

  {
    const int base = wg * 2304 + lane * 36;
#pragma unroll
    for (int r = 0; r < 16; r += 4) {
      float4v u0 = *(float4v*)&fsh[base + r];
      acc0[r] += u0[0]; acc0[r + 1] += u0[1];
      acc0[r + 2] += u0[2]; acc0[r + 3] += u0[3];
      float4v u1 = *(float4v*)&fsh[base + 16 + r];
      acc1[r] += u1[0]; acc1[r + 1] += u1[1];
      acc1[r + 2] += u1[2]; acc1[r + 3] += u1[3];
    }
#pragma unroll
    for (int r = 0; r < 16; r++)
      accl[r] += fsh[9216 + wg * 32 + (r & 3) + 8 * (r >> 2) + 4 * hi];
  }

  const size_t obase =
      ((size_t)b * S_ + (size_t)(qt * 128 + wg * 32)) * D_ + h * 64 + l31;
#pragma unroll
  for (int r = 0; r < 16; r++) {
    int q = (r & 3) + 8 * (r >> 2) + 4 * hi;
    float rl = 1.0f / accl[r];
    Ao[obase + (size_t)q * D_]      = f2bf(acc0[r] * rl);
    Ao[obase + (size_t)q * D_ + 32] = f2bf(acc1[r] * rl);
  }
}

// ---------------------------------------------------------------------------
// Output projection: d_out = Ao[8192,512] @ Wo + bo  (fp32 output)
// ---------------------------------------------------------------------------
__global__ __launch_bounds__(256, 4)
void out_gemm(const short* __restrict__ A, const short* __restrict__ Bt,
              const float* __restrict__ bias, float* __restrict__ out) {
  __shared__ __align__(16) short ABs[2 * 8192];   // 32 KiB
  const int m0 = blockIdx.x * 128, n0 = blockIdx.y * 128;

  float4v acc[4][4];
#pragma unroll
  for (int mi = 0; mi < 4; mi++)
#pragma unroll
    for (int ni = 0; ni < 4; ni++) acc[mi][ni] = (float4v){0.f, 0.f, 0.f, 0.f};

  gemm_core3(A, Bt, m0, n0, ABs, acc);

  const int lane = threadIdx.x & 63, wave = threadIdx.x >> 6;
  const int quad = lane >> 4, l16 = lane & 15;
  const int wm = (wave >> 1) * 64, wn = (wave & 1) * 64;
#pragma unroll
  for (int mi = 0; mi < 4; mi++) {
    int m = m0 + wm + mi * 16 + quad * 4;
#pragma unroll
    for (int ni = 0; ni < 4; ni++) {
      int n = n0 + wn + ni * 16 + l16;
      float bb = bias[n];
#pragma unroll
      for (int r = 0; r < 4; r++)
        out[(size_t)(m + r) * 512 + n] = acc[mi][ni][r] + bb;
    }
  }
}

// ---------------------------------------------------------------------------
extern "C" void kernel_launch(void* const* d_in, const int* in_sizes, int n_in,
                              void* d_out, int out_size, void* d_ws, size_t ws_size,
                              hipStream_t stream) {
  const float* qin = (const float*)d_in[0];
  const float* kin = (const float*)d_in[1];
  const float* vin = (const float*)d_in[2];
  const float* Wq  = (const float*)d_in[3];
  const float* bq  = (const float*)d_in[4];
  const float* Wk  = (const float*)d_in[5];
  const float* bk  = (const float*)d_in[6];
  const float* Wv  = (const float*)d_in[7];
  const float* bv  = (const float*)d_in[8];
  const float* Wo  = (const float*)d_in[9];
  const float* bo  = (const float*)d_in[10];
  float* out = (float*)d_out;
  short* ws  = (short*)d_ws;

  const size_t NTOK = (size_t)B_ * S_ * D_;  // 4,194,304 elements
  short* Qp  = ws;                 // [B,H,S,64]  bf16 (pre-scaled)
  short* Kp  = ws + NTOK;          // [B,H,S,64]  bf16
  short* Vt  = ws + 2 * NTOK;      // [B,H,64,S]  bf16
  short* Ao  = ws + 3 * NTOK;      // [B,S,512]   bf16
  short* WqT = ws + 4 * NTOK;      // [512,512] each, bf16
  short* WkT = WqT + 512 * 512;
  short* WvT = WkT + 512 * 512;
  short* WoT = WvT + 512 * 512;
  short* Xb  = WoT + 512 * 512;    // [3][8192,512] bf16 converted inputs

  prep<<<dim3(6400), 256, 0, stream>>>(qin, kin, vin, Xb, Wq, Wk, Wv, Wo,
                                       WqT, WkT, WvT, WoT);
  qkv_gemm<<<dim3(64, 4, 3), 256, 0, stream>>>(Xb, WqT, WkT, WvT,
                                               bq, bk, bv, Qp, Kp, Vt);
  attn_kernel<<<dim3(16, 32), 512, 0, stream>>>(Qp, Kp, Vt, Ao);
  out_gemm<<<dim3(64, 4), 256, 0, stream>>>(Ao, WoT, bo, out);
}

// Round 10
// 188.489 us; speedup vs baseline: 1.0280x; 1.0280x over previous
//
#include <hip/hip_runtime.h>
#include <hip/hip_bf16.h>

using bf16 = __hip_bfloat16;
typedef short short8  __attribute__((ext_vector_type(8)));
typedef short short4v __attribute__((ext_vector_type(4)));
typedef float float4v __attribute__((ext_vector_type(4)));
typedef float f32x16  __attribute__((ext_vector_type(16)));
typedef unsigned int uint4v __attribute__((ext_vector_type(4)));

#define MFMA_BF16   __builtin_amdgcn_mfma_f32_16x16x32_bf16
#define MFMA32_BF16 __builtin_amdgcn_mfma_f32_32x32x16_bf16

// Problem constants
#define B_  4
#define S_  2048
#define D_  512
#define H_  8
#define DK_ 64

__device__ __forceinline__ short f2bf(float f) {
  bf16 h = __float2bfloat16(f);
  return *reinterpret_cast<short*>(&h);
}

__device__ __forceinline__ unsigned cvtpk(float lo, float hi) {
  unsigned r;
  asm("v_cvt_pk_bf16_f32 %0, %1, %2" : "=v"(r) : "v"(lo), "v"(hi));
  return r;
}

__device__ __forceinline__ void plswap(unsigned& a, unsigned& b) {
  asm("v_permlane32_swap_b32 %0, %1" : "+v"(a), "+v"(b));
}

__device__ __forceinline__ short8 mk8(unsigned v0, unsigned v1, unsigned v2,
                                      unsigned v3) {
  uint4v u;
  u[0] = v0; u[1] = v1; u[2] = v2; u[3] = v3;
  return __builtin_bit_cast(short8, u);
}

#define GLL(g, l) __builtin_amdgcn_global_load_lds(                        \
      (const __attribute__((address_space(1))) void*)(g),                  \
      (__attribute__((address_space(3))) void*)(l), 16, 0, 0)

// ---------------------------------------------------------------------------
// prep: (blocks 0..6143) fp32->bf16 conversion of q/k/v inputs -> Xb,
//       (blocks 6144..6399) weight transpose -> canonical bf16 B^T layout.
// ---------------------------------------------------------------------------
__global__ __launch_bounds__(256)
void prep(const float* __restrict__ qin, const float* __restrict__ kin,
          const float* __restrict__ vin, short* __restrict__ Xb,
          const float* __restrict__ Wq, const float* __restrict__ Wk,
          const float* __restrict__ Wv, const float* __restrict__ Wo,
          short* __restrict__ WqT, short* __restrict__ WkT,
          short* __restrict__ WvT, short* __restrict__ WoT) {
  __shared__ float tile[64 * 65];
  const int bid = blockIdx.x, tid = threadIdx.x;
  const size_t NTOK = (size_t)B_ * S_ * D_;

  if (bid < 6144) {
    const int z = bid >> 11, blk = bid & 2047;
    const float* src = (z == 0) ? qin : (z == 1) ? kin : vin;
    short* dst = Xb + (size_t)z * NTOK;
    const size_t base = ((size_t)blk * 256 + tid) * 8;
    float4v f0 = *(const float4v*)&src[base];
    float4v f1 = *(const float4v*)&src[base + 4];
    short8 s;
#pragma unroll
    for (int j = 0; j < 4; j++) { s[j] = f2bf(f0[j]); s[j + 4] = f2bf(f1[j]); }
    *(short8*)&dst[base] = s;
    return;
  }

  const int tw = bid - 6144;
  const int mat = tw >> 6, t = tw & 63;
  const float* W = (mat == 0) ? Wq : (mat == 1) ? Wk : (mat == 2) ? Wv : Wo;
  short* T       = (mat == 0) ? WqT : (mat == 1) ? WkT : (mat == 2) ? WvT : WoT;

  size_t sbase, ss, dbase;
  if (mat < 3) {
    int hh = t >> 3, d0 = (t & 7) * 64;
    sbase = (size_t)hh * 32768 + (size_t)d0 * 64;
    ss = 64;
    dbase = (size_t)hh * 64 * 512 + d0;
  } else {
    int n0 = (t >> 3) * 64, k0 = (t & 7) * 64;
    sbase = (size_t)k0 * 512 + n0;
    ss = 512;
    dbase = (size_t)n0 * 512 + k0;
  }

  {
    int r = tid >> 2, c0 = (tid & 3) * 16;
#pragma unroll
    for (int j = 0; j < 4; j++)
      *(float4v*)&tile[r * 65 + c0 + j * 4] =
          *(const float4v*)&W[sbase + (size_t)r * ss + c0 + j * 4];
  }
  __syncthreads();
  {
    int c = tid >> 2, r0 = (tid & 3) * 16;
#pragma unroll
    for (int j = 0; j < 2; j++) {
      short8 s;
#pragma unroll
      for (int u = 0; u < 8; u++) s[u] = f2bf(tile[(r0 + j * 8 + u) * 65 + c]);
      *(short8*)&T[dbase + (size_t)c * 512 + r0 + j * 8] = s;
    }
  }
}

// ---------------------------------------------------------------------------
// GEMM core v4: C[128x128] = A[128x512] * Bt[128x512]^T, all-bf16.
// BK=32, THREE-BUFFER pipeline with COUNTED vmcnt (T4): per K-step
//   [vmcnt(4); s_barrier; stage(s+2); comp(s)]
// -- only the CURRENT tile's 4 loads are waited on (issued a full iteration
// earlier, latency hidden); the next tile's 4 stay in flight ACROSS the
// barrier (never drain to 0 mid-loop). Buffer safety: (s+2)%3 != (s+1)%3
// != s%3, and the iter-s barrier guarantees all waves finished comp(s-1)
// before stage(s+2) overwrites its buffer.
// Interleaved A|B LDS tile, involution p = c ^ (row&7) on the per-lane
// GLOBAL source (LDS dest linear -- rule #21); conflict-free ds_read_b128.
// LDS 48 KiB -> 3 blocks/CU.
// ---------------------------------------------------------------------------
__device__ __forceinline__ void gemm_core4(const short* __restrict__ A,
                                           const short* __restrict__ Bt,
                                           int m0, int n0,
                                           short* ABs,
                                           float4v acc[4][4]) {
  const int tid  = threadIdx.x;
  const int lane = tid & 63, wave = tid >> 6;
  const int quad = lane >> 4, l16 = lane & 15;
  const int wm = (wave >> 1) * 64, wn = (wave & 1) * 64;

  auto stage = [&](int buf, int k0) {
#pragma unroll
    for (int i = 0; i < 4; i++) {
      int q = (wave * 4 + i) * 64 + lane;      // chunk id 0..1023
      int row = q >> 3, p = q & 7;
      int c = p ^ (row & 7);                    // logical chunk at this slot
      const short* src = (c < 4)
          ? &A [(size_t)(m0 + row) * 512 + k0 + c * 8]
          : &Bt[(size_t)(n0 + row) * 512 + k0 + (c - 4) * 8];
      GLL(src, &ABs[buf * 8192 + (wave * 4 + i) * 512]);
    }
  };
  auto comp = [&](int buf) {
    short8 af[4], bfr[4];
#pragma unroll
    for (int mi = 0; mi < 4; mi++) {
      int row = wm + mi * 16 + l16;
      af[mi] = *(short8*)&ABs[buf * 8192 + row * 64 + ((quad ^ (row & 7)) << 3)];
    }
#pragma unroll
    for (int ni = 0; ni < 4; ni++) {
      int row = wn + ni * 16 + l16;
      bfr[ni] = *(short8*)&ABs[buf * 8192 + row * 64 +
                               (((4 + quad) ^ (row & 7)) << 3)];
    }
#pragma unroll
    for (int mi = 0; mi < 4; mi++)
#pragma unroll
      for (int ni = 0; ni < 4; ni++)
        acc[mi][ni] = MFMA_BF16(af[mi], bfr[ni], acc[mi][ni], 0, 0, 0);
  };

  stage(0, 0);      // tile 0
  stage(1, 32);     // tile 1
#pragma unroll
  for (int s = 0; s < 16; s++) {
    // wait for tile s only (4 newest loads = tile s+1 may stay in flight)
    if (s < 15) asm volatile("s_waitcnt vmcnt(4)" ::: "memory");
    else        asm volatile("s_waitcnt vmcnt(0)" ::: "memory");
    __builtin_amdgcn_sched_barrier(0);
    __builtin_amdgcn_s_barrier();
    __builtin_amdgcn_sched_barrier(0);
    if (s + 2 < 16) stage((s + 2) % 3, (s + 2) * 32);
    comp(s % 3);
  }
}

// ---------------------------------------------------------------------------
// QKV projection from pre-converted bf16 Xb. z=0: Q (scaled log2e/8); z=1: K;
// z=2: V -> transposed [B,H,64,S] (round-7 layout: C[s][hv], short4v stores).
// ---------------------------------------------------------------------------
__global__ __launch_bounds__(256, 3)
void qkv_gemm(const short* __restrict__ Xb,
              const short* __restrict__ WqT, const short* __restrict__ WkT,
              const short* __restrict__ WvT,
              const float* __restrict__ bq, const float* __restrict__ bk,
              const float* __restrict__ bv,
              short* __restrict__ Qp, short* __restrict__ Kp,
              short* __restrict__ Vt) {
  __shared__ __align__(16) short ABs[3 * 8192];   // 48 KiB
  const int m0 = blockIdx.x * 128, n0 = blockIdx.y * 128;
  const int z = blockIdx.z;
  const size_t NTOK = (size_t)B_ * S_ * D_;
  const short* A    = Xb + (size_t)z * NTOK;
  const short* Bt   = (z == 0) ? WqT : (z == 1) ? WkT : WvT;
  const float* bias = (z == 0) ? bq  : (z == 1) ? bk  : bv;
  const float scale = (z == 0) ? 0.125f * 1.44269504088896f : 1.0f;

  float4v acc[4][4];
#pragma unroll
  for (int mi = 0; mi < 4; mi++)
#pragma unroll
    for (int ni = 0; ni < 4; ni++) acc[mi][ni] = (float4v){0.f, 0.f, 0.f, 0.f};

  gemm_core4(A, Bt, m0, n0, ABs, acc);

  const int lane = threadIdx.x & 63, wave = threadIdx.x >> 6;
  const int quad = lane >> 4, l16 = lane & 15;
  const int wm = (wave >> 1) * 64, wn = (wave & 1) * 64;

  if (z < 2) {
    short* out = (z == 0) ? Qp : Kp;
#pragma unroll
    for (int mi = 0; mi < 4; mi++) {
      int m = m0 + wm + mi * 16 + quad * 4;
      int b = m >> 11, s = m & 2047;
#pragma unroll
      for (int ni = 0; ni < 4; ni++) {
        int n = n0 + wn + ni * 16 + l16;
        int h = n >> 6, dk = n & 63;
        float bb = bias[n];
        size_t base = (((size_t)b * H_ + h) * S_ + s) * 64 + dk;
#pragma unroll
        for (int r = 0; r < 4; r++)
          out[base + (size_t)r * 64] = f2bf((acc[mi][ni][r] + bb) * scale);
      }
    }
  } else {
#pragma unroll
    for (int mi = 0; mi < 4; mi++) {
      int m = m0 + wm + mi * 16 + quad * 4;
      int b = m >> 11, s = m & 2047;
#pragma unroll
      for (int ni = 0; ni < 4; ni++) {
        int n = n0 + wn + ni * 16 + l16;
        int h = n >> 6, v = n & 63;
        float bb = bias[n];
        short4v pk;
#pragma unroll
        for (int r = 0; r < 4; r++) pk[r] = f2bf(acc[mi][ni][r] + bb);
        *(short4v*)&Vt[(((size_t)b * H_ + h) * 64 + v) * S_ + s] = pk;
      }
    }
  }
}

// ---------------------------------------------------------------------------
// Flash attention v5 (round-8 passing version, byte-identical -- control):
// 512 thr = 8 waves; waves 0-3 KV [0,1024), waves 4-7 KV [1024,2048) for the
// same 128 Q rows. Swapped-operand 32x32x16 MFMA, in-register softmax
// (cvt_pk+permlane32). Row-sum l on the MFMA pipe via ones-vector.
// No-rescale softmax; halves combined through LDS at the end.
// ---------------------------------------------------------------------------
__global__ __launch_bounds__(512, 4)
void attn_kernel(const short* __restrict__ Qp, const short* __restrict__ Kp,
                 const short* __restrict__ Vt, short* __restrict__ Ao) {
  __shared__ __align__(16) short sh[32768];   // 64 KiB

  const int orig = blockIdx.y * gridDim.x + blockIdx.x;
  const int lb = (orig & 7) * 64 + (orig >> 3);   // bijective XCD swizzle
  const int qt = lb & 15, bh = lb >> 4;
  const int b = bh >> 3, h = bh & 7;

  const int tid = threadIdx.x;
  const int lane = tid & 63, wave = tid >> 6;
  const int wg = wave & 3, half = wave >> 2;
  const int l31 = lane & 31, hi = lane >> 5, s7 = l31 & 7;

  const short* Qb = Qp + (size_t)bh * S_ * 64;
  const short* Kb = Kp + (size_t)bh * S_ * 64 + (size_t)half * 1024 * 64;
  const short* Vb = Vt + (size_t)bh * 64 * S_;

  short8 qf[4];
  {
    const short* qrow = Qb + (size_t)(qt * 128 + wg * 32 + l31) * 64;
#pragma unroll
    for (int w = 0; w < 4; w++)
      qf[w] = *(const short8*)&qrow[w * 16 + hi * 8];
  }

  short8 ones8;
#pragma unroll
  for (int j = 0; j < 8; j++) ones8[j] = (short)0x3F80;   // bf16 1.0

  const int slot0 = wg * 128 + lane;
  const int kr0 = slot0 >> 3, kc0 = slot0 & 7;
  const int kr1 = kr0 + 8;
  const short* kg0 = Kb + (size_t)kr0 * 64 + ((kc0 ^ (kr0 & 7)) << 3);
  const short* kg1 = Kb + (size_t)kr1 * 64 + ((kc0 ^ (kr1 & 7)) << 3);
  const short* vg0 = Vb + (size_t)kr0 * S_ + half * 1024 + ((kc0 ^ (kr0 & 7)) << 3);
  const short* vg1 = Vb + (size_t)kr1 * S_ + half * 1024 + ((kc0 ^ (kr1 & 7)) << 3);

  short* Kbase = sh;            // [half*2+buf][4096]
  short* Vbase = sh + 16384;

  f32x16 acc0, acc1, accl;
#pragma unroll
  for (int r = 0; r < 16; r++) { acc0[r] = 0.f; acc1[r] = 0.f; accl[r] = 0.f; }

  {
    short* kd = Kbase + (half * 2) * 4096 + wg * 1024;
    short* vd = Vbase + (half * 2) * 4096 + wg * 1024;
    GLL(kg0, kd); GLL(kg1, kd + 512);
    GLL(vg0, vd); GLL(vg1, vd + 512);
  }
  __syncthreads();

  for (int t = 0; t < 16; t++) {
    const int cur = t & 1;
    if (t < 15) {
      short* kd = Kbase + (half * 2 + (cur ^ 1)) * 4096 + wg * 1024;
      short* vd = Vbase + (half * 2 + (cur ^ 1)) * 4096 + wg * 1024;
      GLL(kg0 + (size_t)(t + 1) * 4096, kd);
      GLL(kg1 + (size_t)(t + 1) * 4096, kd + 512);
      GLL(vg0 + (size_t)(t + 1) * 64, vd);
      GLL(vg1 + (size_t)(t + 1) * 64, vd + 512);
    }
    const short* kb = Kbase + (half * 2 + cur) * 4096;
    const short* vs = Vbase + (half * 2 + cur) * 4096;

#pragma unroll
    for (int kt = 0; kt < 2; kt++) {
      f32x16 sa;
#pragma unroll
      for (int r = 0; r < 16; r++) sa[r] = 0.f;
      __builtin_amdgcn_s_setprio(1);
#pragma unroll
      for (int w = 0; w < 4; w++) {
        short8 kf = *(const short8*)&kb[(kt * 32 + l31) * 64 +
                                        (((2 * w + hi) ^ s7) << 3)];
        sa = MFMA32_BF16(kf, qf[w], sa, 0, 0, 0);
      }
      __builtin_amdgcn_s_setprio(0);

      float pv[16];
#pragma unroll
      for (int r = 0; r < 16; r++) pv[r] = exp2f(sa[r]);

      unsigned a0 = cvtpk(pv[0], pv[1]),  b0 = cvtpk(pv[4], pv[5]);
      plswap(a0, b0);
      unsigned c0 = cvtpk(pv[2], pv[3]),  d0 = cvtpk(pv[6], pv[7]);
      plswap(c0, d0);
      short8 pa0 = mk8(a0, c0, b0, d0);
      unsigned a1 = cvtpk(pv[8], pv[9]),  b1 = cvtpk(pv[12], pv[13]);
      plswap(a1, b1);
      unsigned c1 = cvtpk(pv[10], pv[11]), d1 = cvtpk(pv[14], pv[15]);
      plswap(c1, d1);
      short8 pa1 = mk8(a1, c1, b1, d1);

      __builtin_amdgcn_s_setprio(1);
      // row-sum on MFMA pipe: accl[r] = l for q-row crow(r,hi)
      accl = MFMA32_BF16(pa0, ones8, accl, 0, 0, 0);
      accl = MFMA32_BF16(pa1, ones8, accl, 0, 0, 0);
      {
        const int kw0 = kt * 2, kw1 = kt * 2 + 1;
        short8 v00 = *(const short8*)&vs[l31 * 64 + (((2 * kw0 + hi) ^ s7) << 3)];
        short8 v10 = *(const short8*)&vs[(32 + l31) * 64 + (((2 * kw0 + hi) ^ s7) << 3)];
        acc0 = MFMA32_BF16(pa0, v00, acc0, 0, 0, 0);
        acc1 = MFMA32_BF16(pa0, v10, acc1, 0, 0, 0);
        short8 v01 = *(const short8*)&vs[l31 * 64 + (((2 * kw1 + hi) ^ s7) << 3)];
        short8 v11 = *(const short8*)&vs[(32 + l31) * 64 + (((2 * kw1 + hi) ^ s7) << 3)];
        acc0 = MFMA32_BF16(pa1, v01, acc0, 0, 0, 0);
        acc1 = MFMA32_BF16(pa1, v11, acc1, 0, 0, 0);
      }
      __builtin_amdgcn_s_setprio(0);
    }
    __syncthreads();
  }

  // combine halves through LDS (acc0/acc1 per-lane blocks; accl per-row)
  float* fsh = (float*)sh;
  if (half == 1) {
    const int base = wg * 2304 + lane * 36;
#pragma unroll
    for (int r = 0; r < 16; r += 4) {
      *(float4v*)&fsh[base + r] =
          (float4v){acc0[r], acc0[r + 1], acc0[r + 2], acc0[r + 3]};
      *(float4v*)&fsh[base + 16 + r] =
          (float4v){acc1[r], acc1[r + 1], acc1[r + 2], acc1[r + 3]};
    }
    if (l31 == 0) {       // lanes 0 and 32 cover all 32 rows
#pragma unroll
      for (int r = 0; r < 16; r++)
        fsh[9216 + wg * 32 + (r & 3) + 8 * (r >> 2) + 4 * hi] = accl[r];
    }
  }
  __syncthreads();
  if (half == 1) return;

  {
    const int base = wg * 2304 + lane * 36;
#pragma unroll
    for (int r = 0; r < 16; r += 4) {
      float4v u0 = *(float4v*)&fsh[base + r];
      acc0[r] += u0[0]; acc0[r + 1] += u0[1];
      acc0[r + 2] += u0[2]; acc0[r + 3] += u0[3];
      float4v u1 = *(float4v*)&fsh[base + 16 + r];
      acc1[r] += u1[0]; acc1[r + 1] += u1[1];
      acc1[r + 2] += u1[2]; acc1[r + 3] += u1[3];
    }
#pragma unroll
    for (int r = 0; r < 16; r++)
      accl[r] += fsh[9216 + wg * 32 + (r & 3) + 8 * (r >> 2) + 4 * hi];
  }

  const size_t obase =
      ((size_t)b * S_ + (size_t)(qt * 128 + wg * 32)) * D_ + h * 64 + l31;
#pragma unroll
  for (int r = 0; r < 16; r++) {
    int q = (r & 3) + 8 * (r >> 2) + 4 * hi;
    float rl = 1.0f / accl[r];
    Ao[obase + (size_t)q * D_]      = f2bf(acc0[r] * rl);
    Ao[obase + (size_t)q * D_ + 32] = f2bf(acc1[r] * rl);
  }
}

// ---------------------------------------------------------------------------
// Output projection: d_out = Ao[8192,512] @ Wo + bo  (fp32 output)
// ---------------------------------------------------------------------------
__global__ __launch_bounds__(256, 3)
void out_gemm(const short* __restrict__ A, const short* __restrict__ Bt,
              const float* __restrict__ bias, float* __restrict__ out) {
  __shared__ __align__(16) short ABs[3 * 8192];   // 48 KiB
  const int m0 = blockIdx.x * 128, n0 = blockIdx.y * 128;

  float4v acc[4][4];
#pragma unroll
  for (int mi = 0; mi < 4; mi++)
#pragma unroll
    for (int ni = 0; ni < 4; ni++) acc[mi][ni] = (float4v){0.f, 0.f, 0.f, 0.f};

  gemm_core4(A, Bt, m0, n0, ABs, acc);

  const int lane = threadIdx.x & 63, wave = threadIdx.x >> 6;
  const int quad = lane >> 4, l16 = lane & 15;
  const int wm = (wave >> 1) * 64, wn = (wave & 1) * 64;
#pragma unroll
  for (int mi = 0; mi < 4; mi++) {
    int m = m0 + wm + mi * 16 + quad * 4;
#pragma unroll
    for (int ni = 0; ni < 4; ni++) {
      int n = n0 + wn + ni * 16 + l16;
      float bb = bias[n];
#pragma unroll
      for (int r = 0; r < 4; r++)
        out[(size_t)(m + r) * 512 + n] = acc[mi][ni][r] + bb;
    }
  }
}

// ---------------------------------------------------------------------------
extern "C" void kernel_launch(void* const* d_in, const int* in_sizes, int n_in,
                              void* d_out, int out_size, void* d_ws, size_t ws_size,
                              hipStream_t stream) {
  const float* qin = (const float*)d_in[0];
  const float* kin = (const float*)d_in[1];
  const float* vin = (const float*)d_in[2];
  const float* Wq  = (const float*)d_in[3];
  const float* bq  = (const float*)d_in[4];
  const float* Wk  = (const float*)d_in[5];
  const float* bk  = (const float*)d_in[6];
  const float* Wv  = (const float*)d_in[7];
  const float* bv  = (const float*)d_in[8];
  const float* Wo  = (const float*)d_in[9];
  const float* bo  = (const float*)d_in[10];
  float* out = (float*)d_out;
  short* ws  = (short*)d_ws;

  const size_t NTOK = (size_t)B_ * S_ * D_;  // 4,194,304 elements
  short* Qp  = ws;                 // [B,H,S,64]  bf16 (pre-scaled)
  short* Kp  = ws + NTOK;          // [B,H,S,64]  bf16
  short* Vt  = ws + 2 * NTOK;      // [B,H,64,S]  bf16
  short* Ao  = ws + 3 * NTOK;      // [B,S,512]   bf16
  short* WqT = ws + 4 * NTOK;      // [512,512] each, bf16
  short* WkT = WqT + 512 * 512;
  short* WvT = WkT + 512 * 512;
  short* WoT = WvT + 512 * 512;
  short* Xb  = WoT + 512 * 512;    // [3][8192,512] bf16 converted inputs

  prep<<<dim3(6400), 256, 0, stream>>>(qin, kin, vin, Xb, Wq, Wk, Wv, Wo,
                                       WqT, WkT, WvT, WoT);
  qkv_gemm<<<dim3(64, 4, 3), 256, 0, stream>>>(Xb, WqT, WkT, WvT,
                                               bq, bk, bv, Qp, Kp, Vt);
  attn_kernel<<<dim3(16, 32), 512, 0, stream>>>(Qp, Kp, Vt, Ao);
  out_gemm<<<dim3(64, 4), 256, 0, stream>>>(Ao, WoT, bo, out);
}